// Round 1
// baseline (8482.677 us; speedup 1.0000x reference)
//
#include <hip/hip_runtime.h>
#include <cstdint>
#include <cstddef>

#define BB 128    // batch
#define TT 80     // seq
#define EE 100    // emb dim
#define EP 128    // padded emb dim
#define UU 2048   // units
#define G3 6144   // 3*UU

typedef __bf16 bf16x8 __attribute__((ext_vector_type(8)));
typedef float f32x4 __attribute__((ext_vector_type(4)));

static __device__ __forceinline__ unsigned short f2bf(float x) {
  union { float f; unsigned int u; } a; a.f = x;
  unsigned int r = a.u + 0x7fffu + ((a.u >> 16) & 1u);  // RNE
  return (unsigned short)(r >> 16);
}

// Convert fp32 weight (ksrc x 6144, row-major) -> bf16 MFMA-tiled layout.
// dst element ((ct*KC + c)*64 + kb*16 + nl)*8 + j  holds  src[k=c*32+kb*8+j][col=ct*16+nl]
// (zero-padded for k >= ksrc). Lane L of a wave then loads its whole B-fragment
// (B[k=(L>>4)*8+j][n=L&15]) as one contiguous 16B read at tile_base + L*16B.
__global__ void convert_w(const float* __restrict__ src, unsigned short* __restrict__ dst,
                          int ksrc, int kc_shift) {
  int tid = blockIdx.x * 256 + threadIdx.x;
  int nl = tid & 15;
  int kb = (tid >> 4) & 3;
  int kc_mask = (1 << kc_shift) - 1;
  int c  = (tid >> 6) & kc_mask;
  int ct = tid >> (6 + kc_shift);
  int col = ct * 16 + nl;
  int kbase = c * 32 + kb * 8;
  union { unsigned short u[8]; int4 v; } o;
#pragma unroll
  for (int j = 0; j < 8; ++j) {
    int k = kbase + j;
    float v = (k < ksrc) ? src[(size_t)k * G3 + col] : 0.f;
    o.u[j] = f2bf(v);
  }
  *reinterpret_cast<int4*>(dst + (size_t)tid * 8) = o.v;
}

// X[t][b][e] = bf16(emb[tokens[b][t]][e]), e padded to 128 with zeros.
__global__ void embed_k(const int* __restrict__ tokens, const float* __restrict__ emb,
                        unsigned short* __restrict__ X) {
  int idx = blockIdx.x * 256 + threadIdx.x;
  int e = idx & (EP - 1);
  int b = (idx >> 7) & (BB - 1);
  int t = idx >> 14;
  float v = 0.f;
  if (e < EE) {
    int tok = tokens[b * TT + t];
    v = emb[(size_t)tok * EE + e];
  }
  X[idx] = f2bf(v);
}

// One GRU layer step. Grid: 128 blocks (one 16-unit column tile each), 512 threads
// (8 waves; wave w owns batch rows [16w, 16w+16)).
// KX = padded input width (128 for layer0, 2048 for layer1).
template<int KX>
__global__ __launch_bounds__(512) void gru_step(
    const unsigned short* __restrict__ x,        // (128, KX) bf16 row-major
    const unsigned short* __restrict__ wk,       // tiled input-proj weights
    const unsigned short* __restrict__ wr,       // tiled recurrent weights
    const float* __restrict__ bias,              // (2, 6144) fp32
    float* __restrict__ h_f32,                   // (128, 2048) carried state (in/out)
    const unsigned short* __restrict__ h_bf_in,  // (128, 2048) bf16 state (read)
    unsigned short* __restrict__ h_bf_out) {     // (128, 2048) bf16 state (write)
  constexpr int KC1 = KX / 32;
  constexpr int KC2 = UU / 32;   // 64
  int tu = blockIdx.x;           // unit tile, u0 = tu*16
  int lane = threadIdx.x & 63;
  int wave = threadIdx.x >> 6;   // m-tile index 0..7
  int nl = lane & 15;
  int kq = lane >> 4;
  int mrow = wave * 16 + nl;     // A-operand row for this lane

  f32x4 acc[6] = {{0,0,0,0},{0,0,0,0},{0,0,0,0},{0,0,0,0},{0,0,0,0},{0,0,0,0}};

  // --- input projection: acc[0..2] = x @ wk (gates z, r, h) ---
  {
    const unsigned short* xp = x + (size_t)mrow * KX + kq * 8;
    const unsigned short* wp = wk + (size_t)tu * KC1 * 512 + lane * 8;
    for (int c = 0; c < KC1; ++c) {
      bf16x8 a = *reinterpret_cast<const bf16x8*>(xp + c * 32);
#pragma unroll
      for (int g = 0; g < 3; ++g) {
        bf16x8 bfr = *reinterpret_cast<const bf16x8*>(wp + (size_t)g * (128 * KC1 * 512) + (size_t)c * 512);
        acc[g] = __builtin_amdgcn_mfma_f32_16x16x32_bf16(a, bfr, acc[g], 0, 0, 0);
      }
    }
  }
  // --- recurrent projection: acc[3..5] = h @ wr ---
  {
    const unsigned short* hp = h_bf_in + (size_t)mrow * UU + kq * 8;
    const unsigned short* wp = wr + (size_t)tu * KC2 * 512 + lane * 8;
    for (int c = 0; c < KC2; ++c) {
      bf16x8 a = *reinterpret_cast<const bf16x8*>(hp + c * 32);
#pragma unroll
      for (int g = 0; g < 3; ++g) {
        bf16x8 bfr = *reinterpret_cast<const bf16x8*>(wp + (size_t)g * (128 * KC2 * 512) + (size_t)c * 512);
        acc[3 + g] = __builtin_amdgcn_mfma_f32_16x16x32_bf16(a, bfr, acc[3 + g], 0, 0, 0);
      }
    }
  }

  // --- gate math (C/D layout: col = lane&15, row = kq*4 + reg) ---
  int col = tu * 16 + nl;
  float bi0 = bias[0 * UU + col], bi1 = bias[1 * UU + col], bi2 = bias[2 * UU + col];
  float bh0 = bias[G3 + 0 * UU + col], bh1 = bias[G3 + 1 * UU + col], bh2 = bias[G3 + 2 * UU + col];

#pragma unroll
  for (int r = 0; r < 4; ++r) {
    int m = wave * 16 + kq * 4 + r;
    float iz = acc[0][r] + bi0;
    float ir = acc[1][r] + bi1;
    float ih = acc[2][r] + bi2;
    float hz = acc[3][r] + bh0;
    float hr = acc[4][r] + bh1;
    float hh = acc[5][r] + bh2;
    float z  = 1.f / (1.f + __expf(-(iz + hz)));
    float rg = 1.f / (1.f + __expf(-(ir + hr)));
    float cx = ih + rg * hh;
    float cand = 1.f - 2.f / (__expf(2.f * cx) + 1.f);  // tanh(cx)
    size_t off = (size_t)m * UU + col;
    float hold = h_f32[off];
    float hnew = z * hold + (1.f - z) * cand;
    h_f32[off] = hnew;
    h_bf_out[off] = f2bf(hnew);
  }
}

// logits = sigmoid(h1 @ wout + bout): 128 blocks x 64 threads, one row each.
__global__ void out_k(const float* __restrict__ h1, const float* __restrict__ wout,
                      const float* __restrict__ bout, float* __restrict__ out) {
  int row = blockIdx.x;
  int lane = threadIdx.x;
  float s = 0.f;
  for (int i = lane; i < UU; i += 64) s += h1[(size_t)row * UU + i] * wout[i];
#pragma unroll
  for (int off = 32; off > 0; off >>= 1) s += __shfl_down(s, off);
  if (lane == 0) out[row] = 1.f / (1.f + __expf(-(s + bout[0])));
}

extern "C" void kernel_launch(void* const* d_in, const int* in_sizes, int n_in,
                              void* d_out, int out_size, void* d_ws, size_t ws_size,
                              hipStream_t stream) {
  const int*   tokens = (const int*)  d_in[0];
  const float* emb    = (const float*)d_in[1];
  const float* k0     = (const float*)d_in[2];
  const float* r0     = (const float*)d_in[3];
  const float* b0     = (const float*)d_in[4];
  const float* k1     = (const float*)d_in[5];
  const float* r1     = (const float*)d_in[6];
  const float* b1     = (const float*)d_in[7];
  const float* wout   = (const float*)d_in[8];
  const float* bout   = (const float*)d_in[9];
  float* out = (float*)d_out;

  char* ws = (char*)d_ws;
  // byte offsets into workspace (total 80 MiB)
  unsigned short* W0K = (unsigned short*)(ws + 0);          //  1.5 MB (6144 x 128pad)
  unsigned short* W0R = (unsigned short*)(ws + 1572864);    // 25.2 MB (6144 x 2048)
  unsigned short* W1K = (unsigned short*)(ws + 26738688);   // 25.2 MB
  unsigned short* W1R = (unsigned short*)(ws + 51904512);   // 25.2 MB
  unsigned short* X   = (unsigned short*)(ws + 77070336);   //  2.6 MB (80 x 128 x 128)
  float* H0F          = (float*)(ws + 79691776);            //  1 MB
  float* H1F          = (float*)(ws + 80740352);            //  1 MB
  unsigned short* H0B[2] = { (unsigned short*)(ws + 81788928), (unsigned short*)(ws + 82313216) };
  unsigned short* H1B[2] = { (unsigned short*)(ws + 82837504), (unsigned short*)(ws + 83361792) };

  // zero all h state (fp32 + both bf16 ping-pong buffers): 4 MiB
  hipMemsetAsync(ws + 79691776, 0, 4194304, stream);

  // weight conversion to tiled bf16
  convert_w<<<384,  256, 0, stream>>>(k0, W0K, 100,  2);   // KC=4 (K padded to 128)
  convert_w<<<6144, 256, 0, stream>>>(r0, W0R, 2048, 6);   // KC=64
  convert_w<<<6144, 256, 0, stream>>>(k1, W1K, 2048, 6);
  convert_w<<<6144, 256, 0, stream>>>(r1, W1R, 2048, 6);

  // embedding gather (time-major, padded)
  embed_k<<<5120, 256, 0, stream>>>(tokens, emb, X);

  // 80 sequential steps, 2 layers each
  for (int t = 0; t < TT; ++t) {
    int p = t & 1;
    gru_step<EP><<<128, 512, 0, stream>>>(X + (size_t)t * BB * EP, W0K, W0R, b0,
                                          H0F, H0B[p], H0B[p ^ 1]);
    gru_step<UU><<<128, 512, 0, stream>>>(H0B[p ^ 1], W1K, W1R, b1,
                                          H1F, H1B[p], H1B[p ^ 1]);
  }

  out_k<<<128, 64, 0, stream>>>(H1F, wout, bout, out);
}

// Round 2
// 6079.822 us; speedup vs baseline: 1.3952x; 1.3952x over previous
//
#include <hip/hip_runtime.h>
#include <cstdint>
#include <cstddef>

#define BB 128    // batch
#define TT 80     // seq
#define EE 100    // emb dim
#define EP 128    // padded emb dim
#define UU 2048   // units
#define G3 6144   // 3*UU
#define PLANE (BB * UU)   // 262144 elements, one gate pre-activation plane

typedef __bf16 bf16x8 __attribute__((ext_vector_type(8)));
typedef float f32x4 __attribute__((ext_vector_type(4)));

static __device__ __forceinline__ unsigned short f2bf(float x) {
  union { float f; unsigned int u; } a; a.f = x;
  unsigned int r = a.u + 0x7fffu + ((a.u >> 16) & 1u);  // RNE
  return (unsigned short)(r >> 16);
}

static __device__ __forceinline__ float sigf(float x) {
  return 1.f / (1.f + __expf(-x));
}
static __device__ __forceinline__ float tanhfast(float x) {
  return 1.f - 2.f / (__expf(2.f * x) + 1.f);
}

// Convert fp32 weight (ksrc x 6144, row-major) -> bf16 MFMA-tiled layout.
// dst element ((ct*KC + c)*64 + kb*16 + nl)*8 + j  holds  src[k=c*32+kb*8+j][col=ct*16+nl]
// (zero-padded for k >= ksrc). Lane L of a wave then loads its whole B-fragment
// (B[k=(L>>4)*8+j][n=L&15]) as one contiguous 16B read at tile_base + L*16B.
__global__ void convert_w(const float* __restrict__ src, unsigned short* __restrict__ dst,
                          int ksrc, int kc_shift) {
  int tid = blockIdx.x * 256 + threadIdx.x;
  int nl = tid & 15;
  int kb = (tid >> 4) & 3;
  int kc_mask = (1 << kc_shift) - 1;
  int c  = (tid >> 6) & kc_mask;
  int ct = tid >> (6 + kc_shift);
  int col = ct * 16 + nl;
  int kbase = c * 32 + kb * 8;
  union { unsigned short u[8]; int4 v; } o;
#pragma unroll
  for (int j = 0; j < 8; ++j) {
    int k = kbase + j;
    float v = (k < ksrc) ? src[(size_t)k * G3 + col] : 0.f;
    o.u[j] = f2bf(v);
  }
  *reinterpret_cast<int4*>(dst + (size_t)tid * 8) = o.v;
}

// X[t][b][e] = bf16(emb[tokens[b][t]][e]), e padded to 128 with zeros.
__global__ void embed_k(const int* __restrict__ tokens, const float* __restrict__ emb,
                        unsigned short* __restrict__ X) {
  int idx = blockIdx.x * 256 + threadIdx.x;
  int e = idx & (EP - 1);
  int b = (idx >> 7) & (BB - 1);
  int t = idx >> 14;
  float v = 0.f;
  if (e < EE) {
    int tok = tokens[b * TT + t];
    v = emb[(size_t)tok * EE + e];
  }
  X[idx] = f2bf(v);
}

// 3-gate GEMM over K = KC*32 for one 16-unit tile: acc[g] += A @ W[gate g].
// A: (128, KC*32) bf16 row-major. W: tiled layout from convert_w.
template<int KC>
static __device__ __forceinline__ void gemm3(
    const unsigned short* __restrict__ A, const unsigned short* __restrict__ W,
    int tu, int lane, int mrow, f32x4* acc) {
  const unsigned short* ap = A + (size_t)mrow * (KC * 32) + (lane >> 4) * 8;
  const unsigned short* wp = W + (size_t)tu * KC * 512 + (size_t)lane * 8;
  for (int c = 0; c < KC; ++c) {
    bf16x8 a = *reinterpret_cast<const bf16x8*>(ap + c * 32);
#pragma unroll
    for (int g = 0; g < 3; ++g) {
      bf16x8 b = *reinterpret_cast<const bf16x8*>(wp + (size_t)g * (128 * KC * 512) + (size_t)c * 512);
      acc[g] = __builtin_amdgcn_mfma_f32_16x16x32_bf16(a, b, acc[g], 0, 0, 0);
    }
  }
}

// Store one f32x4 acc plane into G[m][unit]: C/D layout col=lane&15, row=kq*4+reg.
static __device__ __forceinline__ void store_plane(
    float* __restrict__ G, const f32x4& a, int tu, int wave, int lane) {
  int col = tu * 16 + (lane & 15);
  int kq = lane >> 4;
#pragma unroll
  for (int r = 0; r < 4; ++r) {
    int m = wave * 16 + kq * 4 + r;
    G[(size_t)m * UU + col] = a[r];
  }
}

// Pipelined step dispatch d (0..80): 384 blocks x 512 threads.
//  role 0 (blocks   0-127): gi0 = x(d)@k0, gh0 = h0(d-1)@r0  -> G0 (4 planes)   [d<80]
//  role 1 (blocks 128-255): gi1 = h0(d-1)@k1                 -> G1I (3 planes)  [d>=1]
//  role 2 (blocks 256-383): gh1 = h1(d-2)@r1                 -> G1R (3 planes)  [d>=1]
__global__ __launch_bounds__(512) void step_gemms(
    int d,
    const unsigned short* __restrict__ X,
    const unsigned short* __restrict__ W0K, const unsigned short* __restrict__ W0R,
    const unsigned short* __restrict__ W1K, const unsigned short* __restrict__ W1R,
    const unsigned short* __restrict__ H0B, const unsigned short* __restrict__ H1B,
    float* __restrict__ G0, float* __restrict__ G1I, float* __restrict__ G1R) {
  int role = blockIdx.x >> 7;
  int tu = blockIdx.x & 127;
  int lane = threadIdx.x & 63;
  int wave = threadIdx.x >> 6;
  int mrow = wave * 16 + (lane & 15);

  f32x4 acc[3] = {{0,0,0,0},{0,0,0,0},{0,0,0,0}};

  if (role == 0) {
    if (d >= TT) return;
    f32x4 acci[3] = {{0,0,0,0},{0,0,0,0},{0,0,0,0}};
    gemm3<4>(X + (size_t)d * BB * EP, W0K, tu, lane, mrow, acci);   // input proj
    gemm3<64>(H0B, W0R, tu, lane, mrow, acc);                        // recurrent proj
    // planes: 0 = iz+hz, 1 = ir+hr, 2 = ih, 3 = hh
    store_plane(G0 + 0 * PLANE, acci[0] + acc[0], tu, wave, lane);
    store_plane(G0 + 1 * PLANE, acci[1] + acc[1], tu, wave, lane);
    store_plane(G0 + 2 * PLANE, acci[2], tu, wave, lane);
    store_plane(G0 + 3 * PLANE, acc[2], tu, wave, lane);
  } else if (role == 1) {
    if (d < 1) return;
    gemm3<64>(H0B, W1K, tu, lane, mrow, acc);
    store_plane(G1I + 0 * PLANE, acc[0], tu, wave, lane);
    store_plane(G1I + 1 * PLANE, acc[1], tu, wave, lane);
    store_plane(G1I + 2 * PLANE, acc[2], tu, wave, lane);
  } else {
    if (d < 1) return;
    gemm3<64>(H1B, W1R, tu, lane, mrow, acc);
    store_plane(G1R + 0 * PLANE, acc[0], tu, wave, lane);
    store_plane(G1R + 1 * PLANE, acc[1], tu, wave, lane);
    store_plane(G1R + 2 * PLANE, acc[2], tu, wave, lane);
  }
}

// Gate math + state update for dispatch d: h0(d) [d<80] and h1(d-1) [d>=1].
__global__ __launch_bounds__(256) void gates_k(
    int d,
    const float* __restrict__ G0, const float* __restrict__ G1I, const float* __restrict__ G1R,
    const float* __restrict__ b0, const float* __restrict__ b1,
    float* __restrict__ H0F, unsigned short* __restrict__ H0B,
    float* __restrict__ H1F, unsigned short* __restrict__ H1B) {
  int idx = blockIdx.x * 256 + threadIdx.x;   // (m, u) flattened, m*2048+u
  int u = idx & (UU - 1);
  if (d < TT) {
    float zs = G0[idx]             + b0[u]        + b0[G3 + u];
    float rs = G0[PLANE + idx]     + b0[UU + u]   + b0[G3 + UU + u];
    float ih = G0[2 * PLANE + idx] + b0[2 * UU + u];
    float hh = G0[3 * PLANE + idx] + b0[G3 + 2 * UU + u];
    float z = sigf(zs), r = sigf(rs);
    float cand = tanhfast(ih + r * hh);
    float h = z * H0F[idx] + (1.f - z) * cand;
    H0F[idx] = h;
    H0B[idx] = f2bf(h);
  }
  if (d >= 1) {
    float iz = G1I[idx]             + b1[u];
    float ir = G1I[PLANE + idx]     + b1[UU + u];
    float ih = G1I[2 * PLANE + idx] + b1[2 * UU + u];
    float hz = G1R[idx]             + b1[G3 + u];
    float hr = G1R[PLANE + idx]     + b1[G3 + UU + u];
    float hh = G1R[2 * PLANE + idx] + b1[G3 + 2 * UU + u];
    float z = sigf(iz + hz), r = sigf(ir + hr);
    float cand = tanhfast(ih + r * hh);
    float h = z * H1F[idx] + (1.f - z) * cand;
    H1F[idx] = h;
    H1B[idx] = f2bf(h);
  }
}

// logits = sigmoid(h1 @ wout + bout): 128 blocks x 64 threads, one row each.
__global__ void out_k(const float* __restrict__ h1, const float* __restrict__ wout,
                      const float* __restrict__ bout, float* __restrict__ out) {
  int row = blockIdx.x;
  int lane = threadIdx.x;
  float s = 0.f;
  for (int i = lane; i < UU; i += 64) s += h1[(size_t)row * UU + i] * wout[i];
#pragma unroll
  for (int off = 32; off > 0; off >>= 1) s += __shfl_down(s, off);
  if (lane == 0) out[row] = 1.f / (1.f + __expf(-(s + bout[0])));
}

extern "C" void kernel_launch(void* const* d_in, const int* in_sizes, int n_in,
                              void* d_out, int out_size, void* d_ws, size_t ws_size,
                              hipStream_t stream) {
  const int*   tokens = (const int*)  d_in[0];
  const float* emb    = (const float*)d_in[1];
  const float* k0     = (const float*)d_in[2];
  const float* r0     = (const float*)d_in[3];
  const float* b0     = (const float*)d_in[4];
  const float* k1     = (const float*)d_in[5];
  const float* r1     = (const float*)d_in[6];
  const float* b1     = (const float*)d_in[7];
  const float* wout   = (const float*)d_in[8];
  const float* bout   = (const float*)d_in[9];
  float* out = (float*)d_out;

  char* ws = (char*)d_ws;
  unsigned short* W0K = (unsigned short*)(ws + 0);          //  1.5 MB
  unsigned short* W0R = (unsigned short*)(ws + 1572864);    // 25.2 MB
  unsigned short* W1K = (unsigned short*)(ws + 26738688);   // 25.2 MB
  unsigned short* W1R = (unsigned short*)(ws + 51904512);   // 25.2 MB
  unsigned short* X   = (unsigned short*)(ws + 77070336);   //  2.6 MB
  float* H0F          = (float*)(ws + 79691776);            //  1 MB fp32 state
  float* H1F          = (float*)(ws + 80740352);            //  1 MB
  unsigned short* H0B = (unsigned short*)(ws + 81788928);   //  0.5 MB bf16 state
  unsigned short* H1B = (unsigned short*)(ws + 82313216);   //  0.5 MB
  float* G0           = (float*)(ws + 82837504);            //  4 MB (4 planes)
  float* G1I          = (float*)(ws + 87031808);            //  3 MB (3 planes)
  float* G1R          = (float*)(ws + 90177536);            //  3 MB (3 planes)
  // total ws use: 93,323,264 bytes

  // zero h state (H0F, H1F, H0B, H1B are contiguous): 3 MiB
  hipMemsetAsync(ws + 79691776, 0, 3145728, stream);

  // weight conversion to tiled bf16
  convert_w<<<384,  256, 0, stream>>>(k0, W0K, 100,  2);   // KC=4 (K padded to 128)
  convert_w<<<6144, 256, 0, stream>>>(r0, W0R, 2048, 6);   // KC=64
  convert_w<<<6144, 256, 0, stream>>>(k1, W1K, 2048, 6);
  convert_w<<<6144, 256, 0, stream>>>(r1, W1R, 2048, 6);

  // embedding gather (time-major, padded)
  embed_k<<<5120, 256, 0, stream>>>(tokens, emb, X);

  // 81 pipelined step dispatches: d computes h0(d) and h1(d-1) concurrently
  for (int d = 0; d <= TT; ++d) {
    step_gemms<<<384, 512, 0, stream>>>(d, X, W0K, W0R, W1K, W1R, H0B, H1B,
                                        G0, G1I, G1R);
    gates_k<<<1024, 256, 0, stream>>>(d, G0, G1I, G1R, b0, b1,
                                      H0F, H0B, H1F, H1B);
  }

  out_k<<<128, 64, 0, stream>>>(H1F, wout, bout, out);
}

// Round 3
// 4098.612 us; speedup vs baseline: 2.0696x; 1.4834x over previous
//
#include <hip/hip_runtime.h>
#include <cstdint>
#include <cstddef>

#define BB 128    // batch
#define TT 80     // seq
#define EE 100    // emb dim
#define EP 128    // padded emb dim
#define UU 2048   // units
#define G3 6144   // 3*UU
#define PLANE (BB * UU)   // 262144 elements, one gate pre-activation plane

typedef __bf16 bf16x8 __attribute__((ext_vector_type(8)));
typedef float f32x4 __attribute__((ext_vector_type(4)));

static __device__ __forceinline__ unsigned short f2bf(float x) {
  union { float f; unsigned int u; } a; a.f = x;
  unsigned int r = a.u + 0x7fffu + ((a.u >> 16) & 1u);  // RNE
  return (unsigned short)(r >> 16);
}

static __device__ __forceinline__ float sigf(float x) {
  return 1.f / (1.f + __expf(-x));
}
static __device__ __forceinline__ float tanhfast(float x) {
  return 1.f - 2.f / (__expf(2.f * x) + 1.f);
}

// Convert fp32 weight (ksrc x 6144, row-major) -> bf16 MFMA-tiled layout.
// dst element ((ct*KC + c)*64 + kb*16 + nl)*8 + j  holds  src[k=c*32+kb*8+j][col=ct*16+nl]
__global__ void convert_w(const float* __restrict__ src, unsigned short* __restrict__ dst,
                          int ksrc, int kc_shift) {
  int tid = blockIdx.x * 256 + threadIdx.x;
  int nl = tid & 15;
  int kb = (tid >> 4) & 3;
  int kc_mask = (1 << kc_shift) - 1;
  int c  = (tid >> 6) & kc_mask;
  int ct = tid >> (6 + kc_shift);
  int col = ct * 16 + nl;
  int kbase = c * 32 + kb * 8;
  union { unsigned short u[8]; int4 v; } o;
#pragma unroll
  for (int j = 0; j < 8; ++j) {
    int k = kbase + j;
    float v = (k < ksrc) ? src[(size_t)k * G3 + col] : 0.f;
    o.u[j] = f2bf(v);
  }
  *reinterpret_cast<int4*>(dst + (size_t)tid * 8) = o.v;
}

// X[t][b][e] = bf16(emb[tokens[b][t]][e]), e padded to 128 with zeros.
__global__ void embed_k(const int* __restrict__ tokens, const float* __restrict__ emb,
                        unsigned short* __restrict__ X) {
  int idx = blockIdx.x * 256 + threadIdx.x;
  int e = idx & (EP - 1);
  int b = (idx >> 7) & (BB - 1);
  int t = idx >> 14;
  float v = 0.f;
  if (e < EE) {
    int tok = tokens[b * TT + t];
    v = emb[(size_t)tok * EE + e];
  }
  X[idx] = f2bf(v);
}

// 3-gate GEMM over K-chunk range [c0,c1) for one 16-unit tile.
// Batch-4 on c: 12 independent B-fragment loads in flight per iteration.
template<int WKC>
static __device__ __forceinline__ void gemm3_part(
    const unsigned short* __restrict__ A, int KX,
    const unsigned short* __restrict__ W,
    int c0, int c1, int tu, int lane, int mrow, f32x4* acc) {
  const unsigned short* ap = A + (size_t)mrow * KX + (lane >> 4) * 8 + (size_t)c0 * 32;
  const unsigned short* wp = W + ((size_t)tu * WKC + c0) * 512 + (size_t)lane * 8;
  constexpr size_t GS = (size_t)128 * WKC * 512;   // gate stride in tiled layout
  int n = c1 - c0;
  int c = 0;
  for (; c + 4 <= n; c += 4) {
    bf16x8 b[4][3];
#pragma unroll
    for (int i = 0; i < 4; ++i)
#pragma unroll
      for (int gg = 0; gg < 3; ++gg)
        b[i][gg] = *reinterpret_cast<const bf16x8*>(wp + gg * GS + (size_t)(c + i) * 512);
#pragma unroll
    for (int i = 0; i < 4; ++i) {
      bf16x8 a = *reinterpret_cast<const bf16x8*>(ap + (size_t)(c + i) * 32);
#pragma unroll
      for (int gg = 0; gg < 3; ++gg)
        acc[gg] = __builtin_amdgcn_mfma_f32_16x16x32_bf16(a, b[i][gg], acc[gg], 0, 0, 0);
    }
  }
  for (; c < n; ++c) {
    bf16x8 a = *reinterpret_cast<const bf16x8*>(ap + (size_t)c * 32);
#pragma unroll
    for (int gg = 0; gg < 3; ++gg) {
      bf16x8 bb = *reinterpret_cast<const bf16x8*>(wp + gg * GS + (size_t)c * 512);
      acc[gg] = __builtin_amdgcn_mfma_f32_16x16x32_bf16(a, bb, acc[gg], 0, 0, 0);
    }
  }
}

// Store one f32x4 acc plane into G[m][unit]: C/D layout col=lane&15, row=kq*4+reg.
static __device__ __forceinline__ void store_plane(
    float* __restrict__ G, const f32x4& a, int tu, int wave, int lane) {
  int col = tu * 16 + (lane & 15);
  int kq = lane >> 4;
#pragma unroll
  for (int r = 0; r < 4; ++r) {
    int m = wave * 16 + kq * 4 + r;
    G[(size_t)m * UU + col] = a[r];
  }
}

// Pipelined step dispatch d (0..80): 768 blocks x 512 threads, exactly 3 blocks/CU.
// block = grp*128 + tu;  grp = g*2 + khalf;  g: 0=L0, 1=L1-input, 2=L1-recurrent.
// Split-K: each (g,tu) pair of blocks covers K in two halves; gates_k sums partials.
// Role0 khalf0 also does the (tiny) input projection; K-split 30/34 to balance.
__global__ __launch_bounds__(512, 6) void step_gemms(
    int d,
    const unsigned short* __restrict__ X,
    const unsigned short* __restrict__ W0K, const unsigned short* __restrict__ W0R,
    const unsigned short* __restrict__ W1K, const unsigned short* __restrict__ W1R,
    const unsigned short* __restrict__ H0B, const unsigned short* __restrict__ H1B,
    float* __restrict__ G0, float* __restrict__ G1I, float* __restrict__ G1R) {
  int grp = blockIdx.x >> 7;
  int tu = blockIdx.x & 127;
  int g = grp >> 1;
  int kh = grp & 1;
  int lane = threadIdx.x & 63;
  int wave = threadIdx.x >> 6;
  int mrow = wave * 16 + (lane & 15);

  f32x4 acc[3] = {{0,0,0,0},{0,0,0,0},{0,0,0,0}};

  if (g == 0) {
    if (d >= TT) return;
    if (kh == 0) {
      f32x4 acci[3] = {{0,0,0,0},{0,0,0,0},{0,0,0,0}};
      gemm3_part<4>(X + (size_t)d * BB * EP, EP, W0K, 0, 4, tu, lane, mrow, acci);
      gemm3_part<64>(H0B, UU, W0R, 0, 30, tu, lane, mrow, acc);
      store_plane(G0 + 0 * PLANE, acci[0] + acc[0], tu, wave, lane);  // z partial a
      store_plane(G0 + 1 * PLANE, acci[1] + acc[1], tu, wave, lane);  // r partial a
      store_plane(G0 + 2 * PLANE, acci[2], tu, wave, lane);           // ih (full)
      store_plane(G0 + 3 * PLANE, acc[2], tu, wave, lane);            // hh partial a
    } else {
      gemm3_part<64>(H0B, UU, W0R, 30, 64, tu, lane, mrow, acc);
      store_plane(G0 + 4 * PLANE, acc[0], tu, wave, lane);            // z partial b
      store_plane(G0 + 5 * PLANE, acc[1], tu, wave, lane);            // r partial b
      store_plane(G0 + 6 * PLANE, acc[2], tu, wave, lane);            // hh partial b
    }
  } else if (g == 1) {
    if (d < 1) return;
    gemm3_part<64>(H0B, UU, W1K, kh * 32, kh * 32 + 32, tu, lane, mrow, acc);
    store_plane(G1I + (kh * 3 + 0) * PLANE, acc[0], tu, wave, lane);
    store_plane(G1I + (kh * 3 + 1) * PLANE, acc[1], tu, wave, lane);
    store_plane(G1I + (kh * 3 + 2) * PLANE, acc[2], tu, wave, lane);
  } else {
    if (d < 1) return;
    gemm3_part<64>(H1B, UU, W1R, kh * 32, kh * 32 + 32, tu, lane, mrow, acc);
    store_plane(G1R + (kh * 3 + 0) * PLANE, acc[0], tu, wave, lane);
    store_plane(G1R + (kh * 3 + 1) * PLANE, acc[1], tu, wave, lane);
    store_plane(G1R + (kh * 3 + 2) * PLANE, acc[2], tu, wave, lane);
  }
}

// Gate math + state update for dispatch d: h0(d) [d<80] and h1(d-1) [d>=1].
__global__ __launch_bounds__(256) void gates_k(
    int d,
    const float* __restrict__ G0, const float* __restrict__ G1I, const float* __restrict__ G1R,
    const float* __restrict__ b0, const float* __restrict__ b1,
    float* __restrict__ H0F, unsigned short* __restrict__ H0B,
    float* __restrict__ H1F, unsigned short* __restrict__ H1B) {
  int idx = blockIdx.x * 256 + threadIdx.x;   // (m, u) flattened, m*2048+u
  int u = idx & (UU - 1);
  if (d < TT) {
    float zs = G0[idx] + G0[4 * PLANE + idx]             + b0[u]        + b0[G3 + u];
    float rs = G0[PLANE + idx] + G0[5 * PLANE + idx]     + b0[UU + u]   + b0[G3 + UU + u];
    float ih = G0[2 * PLANE + idx]                       + b0[2 * UU + u];
    float hh = G0[3 * PLANE + idx] + G0[6 * PLANE + idx] + b0[G3 + 2 * UU + u];
    float z = sigf(zs), r = sigf(rs);
    float cand = tanhfast(ih + r * hh);
    float h = z * H0F[idx] + (1.f - z) * cand;
    H0F[idx] = h;
    H0B[idx] = f2bf(h);
  }
  if (d >= 1) {
    float iz = G1I[idx] + G1I[3 * PLANE + idx]             + b1[u];
    float ir = G1I[PLANE + idx] + G1I[4 * PLANE + idx]     + b1[UU + u];
    float ih = G1I[2 * PLANE + idx] + G1I[5 * PLANE + idx] + b1[2 * UU + u];
    float hz = G1R[idx] + G1R[3 * PLANE + idx]             + b1[G3 + u];
    float hr = G1R[PLANE + idx] + G1R[4 * PLANE + idx]     + b1[G3 + UU + u];
    float hh = G1R[2 * PLANE + idx] + G1R[5 * PLANE + idx] + b1[G3 + 2 * UU + u];
    float z = sigf(iz + hz), r = sigf(ir + hr);
    float cand = tanhfast(ih + r * hh);
    float h = z * H1F[idx] + (1.f - z) * cand;
    H1F[idx] = h;
    H1B[idx] = f2bf(h);
  }
}

// logits = sigmoid(h1 @ wout + bout): 128 blocks x 64 threads, one row each.
__global__ void out_k(const float* __restrict__ h1, const float* __restrict__ wout,
                      const float* __restrict__ bout, float* __restrict__ out) {
  int row = blockIdx.x;
  int lane = threadIdx.x;
  float s = 0.f;
  for (int i = lane; i < UU; i += 64) s += h1[(size_t)row * UU + i] * wout[i];
#pragma unroll
  for (int off = 32; off > 0; off >>= 1) s += __shfl_down(s, off);
  if (lane == 0) out[row] = 1.f / (1.f + __expf(-(s + bout[0])));
}

extern "C" void kernel_launch(void* const* d_in, const int* in_sizes, int n_in,
                              void* d_out, int out_size, void* d_ws, size_t ws_size,
                              hipStream_t stream) {
  const int*   tokens = (const int*)  d_in[0];
  const float* emb    = (const float*)d_in[1];
  const float* k0     = (const float*)d_in[2];
  const float* r0     = (const float*)d_in[3];
  const float* b0     = (const float*)d_in[4];
  const float* k1     = (const float*)d_in[5];
  const float* r1     = (const float*)d_in[6];
  const float* b1     = (const float*)d_in[7];
  const float* wout   = (const float*)d_in[8];
  const float* bout   = (const float*)d_in[9];
  float* out = (float*)d_out;

  char* ws = (char*)d_ws;
  unsigned short* W0K = (unsigned short*)(ws + 0);          //  1.5 MB
  unsigned short* W0R = (unsigned short*)(ws + 1572864);    // 25.2 MB
  unsigned short* W1K = (unsigned short*)(ws + 26738688);   // 25.2 MB
  unsigned short* W1R = (unsigned short*)(ws + 51904512);   // 25.2 MB
  unsigned short* X   = (unsigned short*)(ws + 77070336);   //  2.6 MB
  float* H0F          = (float*)(ws + 79691776);            //  1 MB fp32 state
  float* H1F          = (float*)(ws + 80740352);            //  1 MB
  unsigned short* H0B = (unsigned short*)(ws + 81788928);   //  0.5 MB bf16 state
  unsigned short* H1B = (unsigned short*)(ws + 82313216);   //  0.5 MB
  float* G0           = (float*)(ws + 82837504);            //  7 MB (7 planes)
  float* G1I          = (float*)(ws + 90177536);            //  6 MB (6 planes)
  float* G1R          = (float*)(ws + 96468992);            //  6 MB (6 planes)
  // total ws use: 102,760,448 bytes

  // zero h state (H0F, H1F, H0B, H1B are contiguous): 3 MiB
  hipMemsetAsync(ws + 79691776, 0, 3145728, stream);

  // weight conversion to tiled bf16
  convert_w<<<384,  256, 0, stream>>>(k0, W0K, 100,  2);   // KC=4 (K padded to 128)
  convert_w<<<6144, 256, 0, stream>>>(r0, W0R, 2048, 6);   // KC=64
  convert_w<<<6144, 256, 0, stream>>>(k1, W1K, 2048, 6);
  convert_w<<<6144, 256, 0, stream>>>(r1, W1R, 2048, 6);

  // embedding gather (time-major, padded)
  embed_k<<<5120, 256, 0, stream>>>(tokens, emb, X);

  // 81 pipelined step dispatches: d computes h0(d) and h1(d-1) concurrently
  for (int d = 0; d <= TT; ++d) {
    step_gemms<<<768, 512, 0, stream>>>(d, X, W0K, W0R, W1K, W1R, H0B, H1B,
                                        G0, G1I, G1R);
    gates_k<<<1024, 256, 0, stream>>>(d, G0, G1I, G1R, b0, b1,
                                      H0F, H0B, H1F, H1B);
  }

  out_k<<<128, 64, 0, stream>>>(H1F, wout, bout, out);
}

// Round 4
// 3129.386 us; speedup vs baseline: 2.7107x; 1.3097x over previous
//
#include <hip/hip_runtime.h>
#include <cstdint>
#include <cstddef>

#define BB 128    // batch
#define TT 80     // seq
#define EE 100    // emb dim
#define EP 128    // padded emb dim
#define UU 2048   // units
#define G3 6144   // 3*UU
#define PLANE (BB * UU)   // 262144 elements, one gate pre-activation plane

typedef __bf16 bf16x8 __attribute__((ext_vector_type(8)));
typedef float f32x4 __attribute__((ext_vector_type(4)));

static __device__ __forceinline__ unsigned short f2bf(float x) {
  union { float f; unsigned int u; } a; a.f = x;
  unsigned int r = a.u + 0x7fffu + ((a.u >> 16) & 1u);  // RNE
  return (unsigned short)(r >> 16);
}

static __device__ __forceinline__ float sigf(float x) {
  return 1.f / (1.f + __expf(-x));
}
static __device__ __forceinline__ float tanhfast(float x) {
  return 1.f - 2.f / (__expf(2.f * x) + 1.f);
}

// async global -> LDS, 16B per lane. LDS dest is wave-uniform base + lane*16.
static __device__ __forceinline__ void gload_lds16(const unsigned short* g, unsigned short* l) {
  __builtin_amdgcn_global_load_lds(
      (const __attribute__((address_space(1))) void*)g,
      (__attribute__((address_space(3))) void*)l,
      16, 0, 0);
}

// Convert fp32 weight (ksrc x 6144, row-major) -> bf16 MFMA-tiled layout.
// dst element ((ct*KC + c)*64 + kb*16 + nl)*8 + j  holds  src[k=c*32+kb*8+j][col=ct*16+nl]
__global__ void convert_w(const float* __restrict__ src, unsigned short* __restrict__ dst,
                          int ksrc, int kc_shift) {
  int tid = blockIdx.x * 256 + threadIdx.x;
  int nl = tid & 15;
  int kb = (tid >> 4) & 3;
  int kc_mask = (1 << kc_shift) - 1;
  int c  = (tid >> 6) & kc_mask;
  int ct = tid >> (6 + kc_shift);
  int col = ct * 16 + nl;
  int kbase = c * 32 + kb * 8;
  union { unsigned short u[8]; int4 v; } o;
#pragma unroll
  for (int j = 0; j < 8; ++j) {
    int k = kbase + j;
    float v = (k < ksrc) ? src[(size_t)k * G3 + col] : 0.f;
    o.u[j] = f2bf(v);
  }
  *reinterpret_cast<int4*>(dst + (size_t)tid * 8) = o.v;
}

// X[t][b][e] = bf16(emb[tokens[b][t]][e]), e padded to 128 with zeros.
__global__ void embed_k(const int* __restrict__ tokens, const float* __restrict__ emb,
                        unsigned short* __restrict__ X) {
  int idx = blockIdx.x * 256 + threadIdx.x;
  int e = idx & (EP - 1);
  int b = (idx >> 7) & (BB - 1);
  int t = idx >> 14;
  float v = 0.f;
  if (e < EE) {
    int tok = tokens[b * TT + t];
    v = emb[(size_t)tok * EE + e];
  }
  X[idx] = f2bf(v);
}

// Store one f32x4 acc plane into G[m][unit]: C/D layout col=lane&15, row=kq*4+reg.
static __device__ __forceinline__ void store_plane(
    float* __restrict__ G, const f32x4& a, int tu, int wave, int lane) {
  int col = tu * 16 + (lane & 15);
  int kq = lane >> 4;
#pragma unroll
  for (int r = 0; r < 4; ++r) {
    int m = wave * 16 + kq * 4 + r;
    G[(size_t)m * UU + col] = a[r];
  }
}

// Pipelined step dispatch d (0..80): 768 blocks x 512 threads, 3 blocks/CU.
// block = grp*128 + tu;  grp = g*2 + khalf;  g: 0=L0, 1=L1-input, 2=L1-recurrent.
// Weight tile (16 cols x 1024 K x 3 gates = 96 KB) streamed via async
// global_load_lds into double-buffered LDS (4 chunks of 24 KB); each byte
// fetched once per block; all 8 waves consume B-fragments from LDS.
__global__ __launch_bounds__(512, 6) void step_gemms(
    int d,
    const unsigned short* __restrict__ X,
    const unsigned short* __restrict__ W0K, const unsigned short* __restrict__ W0R,
    const unsigned short* __restrict__ W1K, const unsigned short* __restrict__ W1R,
    const unsigned short* __restrict__ H0B, const unsigned short* __restrict__ H1B,
    float* __restrict__ G0, float* __restrict__ G1I, float* __restrict__ G1R) {
  int grp = blockIdx.x >> 7;
  int tu = blockIdx.x & 127;
  int g = grp >> 1;
  int kh = grp & 1;
  int lane = threadIdx.x & 63;
  int wave = threadIdx.x >> 6;
  int nl = lane & 15;
  int kq = lane >> 4;
  int mrow = wave * 16 + nl;

  __shared__ unsigned short sbuf[2][24 * 512];   // 2 x 24 KB weight chunks

  const unsigned short* A;
  const unsigned short* W;
  if (g == 0)      { if (d >= TT) return; A = H0B; W = W0R; }
  else if (g == 1) { if (d <  1)  return; A = H0B; W = W1K; }
  else             { if (d <  1)  return; A = H1B; W = W1R; }

  f32x4 acc[3]  = {{0,0,0,0},{0,0,0,0},{0,0,0,0}};
  f32x4 acci[3] = {{0,0,0,0},{0,0,0,0},{0,0,0,0}};

  // role0 khalf0: tiny input projection (K=128 padded), direct loads (L2-hot)
  if (g == 0 && kh == 0) {
    const unsigned short* xp = X + (size_t)d * BB * EP + (size_t)mrow * EP + kq * 8;
    const unsigned short* wp = W0K + (size_t)tu * 4 * 512 + (size_t)lane * 8;
#pragma unroll
    for (int c = 0; c < 4; ++c) {
      bf16x8 a = *reinterpret_cast<const bf16x8*>(xp + c * 32);
#pragma unroll
      for (int gg = 0; gg < 3; ++gg) {
        bf16x8 b = *reinterpret_cast<const bf16x8*>(wp + (size_t)gg * (128 * 4 * 512) + (size_t)c * 512);
        acci[gg] = __builtin_amdgcn_mfma_f32_16x16x32_bf16(a, b, acci[gg], 0, 0, 0);
      }
    }
  }

  const int c0 = kh * 32;                      // this block's K-chunk base
  const unsigned short* ap = A + (size_t)mrow * UU + kq * 8;
  const unsigned short* wlane = W + (size_t)tu * 64 * 512 + (size_t)lane * 8;
  const size_t GS = (size_t)128 * 64 * 512;    // gate stride in tiled layout

  // prologue: stage chunk 0 (8 kc x 3 gates; wave w stages kc = c0+w)
  {
    const unsigned short* src = wlane + (size_t)(c0 + wave) * 512;
    unsigned short* dst = &sbuf[0][(wave * 3) * 512];
#pragma unroll
    for (int gg = 0; gg < 3; ++gg) gload_lds16(src + (size_t)gg * GS, dst + gg * 512);
  }
  __syncthreads();

  for (int it = 0; it < 4; ++it) {
    if (it < 3) {   // stage next chunk async into the other buffer
      const unsigned short* src = wlane + (size_t)(c0 + (it + 1) * 8 + wave) * 512;
      unsigned short* dst = &sbuf[(it + 1) & 1][(wave * 3) * 512];
#pragma unroll
      for (int gg = 0; gg < 3; ++gg) gload_lds16(src + (size_t)gg * GS, dst + gg * 512);
    }
    // compute current chunk from LDS
#pragma unroll
    for (int h = 0; h < 2; ++h) {
      bf16x8 a[4];
#pragma unroll
      for (int j = 0; j < 4; ++j)
        a[j] = *reinterpret_cast<const bf16x8*>(ap + (size_t)(c0 + it * 8 + h * 4 + j) * 32);
#pragma unroll
      for (int j = 0; j < 4; ++j) {
#pragma unroll
        for (int gg = 0; gg < 3; ++gg) {
          bf16x8 b = *reinterpret_cast<const bf16x8*>(
              &sbuf[it & 1][((h * 4 + j) * 3 + gg) * 512 + lane * 8]);
          acc[gg] = __builtin_amdgcn_mfma_f32_16x16x32_bf16(a[j], b, acc[gg], 0, 0, 0);
        }
      }
    }
    __syncthreads();   // drains staged loads; guards buffer reuse
  }

  // epilogue: write gate pre-activation planes
  if (g == 0) {
    if (kh == 0) {
      store_plane(G0 + 0 * PLANE, acci[0] + acc[0], tu, wave, lane);  // z partial a (+input)
      store_plane(G0 + 1 * PLANE, acci[1] + acc[1], tu, wave, lane);  // r partial a (+input)
      store_plane(G0 + 2 * PLANE, acci[2], tu, wave, lane);           // ih (full)
      store_plane(G0 + 3 * PLANE, acc[2], tu, wave, lane);            // hh partial a
    } else {
      store_plane(G0 + 4 * PLANE, acc[0], tu, wave, lane);            // z partial b
      store_plane(G0 + 5 * PLANE, acc[1], tu, wave, lane);            // r partial b
      store_plane(G0 + 6 * PLANE, acc[2], tu, wave, lane);            // hh partial b
    }
  } else if (g == 1) {
    store_plane(G1I + (kh * 3 + 0) * PLANE, acc[0], tu, wave, lane);
    store_plane(G1I + (kh * 3 + 1) * PLANE, acc[1], tu, wave, lane);
    store_plane(G1I + (kh * 3 + 2) * PLANE, acc[2], tu, wave, lane);
  } else {
    store_plane(G1R + (kh * 3 + 0) * PLANE, acc[0], tu, wave, lane);
    store_plane(G1R + (kh * 3 + 1) * PLANE, acc[1], tu, wave, lane);
    store_plane(G1R + (kh * 3 + 2) * PLANE, acc[2], tu, wave, lane);
  }
}

// Gate math + state update for dispatch d: h0(d) [d<80] and h1(d-1) [d>=1].
__global__ __launch_bounds__(256) void gates_k(
    int d,
    const float* __restrict__ G0, const float* __restrict__ G1I, const float* __restrict__ G1R,
    const float* __restrict__ b0, const float* __restrict__ b1,
    float* __restrict__ H0F, unsigned short* __restrict__ H0B,
    float* __restrict__ H1F, unsigned short* __restrict__ H1B) {
  int idx = blockIdx.x * 256 + threadIdx.x;   // (m, u) flattened, m*2048+u
  int u = idx & (UU - 1);
  if (d < TT) {
    float zs = G0[idx] + G0[4 * PLANE + idx]             + b0[u]        + b0[G3 + u];
    float rs = G0[PLANE + idx] + G0[5 * PLANE + idx]     + b0[UU + u]   + b0[G3 + UU + u];
    float ih = G0[2 * PLANE + idx]                       + b0[2 * UU + u];
    float hh = G0[3 * PLANE + idx] + G0[6 * PLANE + idx] + b0[G3 + 2 * UU + u];
    float z = sigf(zs), r = sigf(rs);
    float cand = tanhfast(ih + r * hh);
    float h = z * H0F[idx] + (1.f - z) * cand;
    H0F[idx] = h;
    H0B[idx] = f2bf(h);
  }
  if (d >= 1) {
    float iz = G1I[idx] + G1I[3 * PLANE + idx]             + b1[u];
    float ir = G1I[PLANE + idx] + G1I[4 * PLANE + idx]     + b1[UU + u];
    float ih = G1I[2 * PLANE + idx] + G1I[5 * PLANE + idx] + b1[2 * UU + u];
    float hz = G1R[idx] + G1R[3 * PLANE + idx]             + b1[G3 + u];
    float hr = G1R[PLANE + idx] + G1R[4 * PLANE + idx]     + b1[G3 + UU + u];
    float hh = G1R[2 * PLANE + idx] + G1R[5 * PLANE + idx] + b1[G3 + 2 * UU + u];
    float z = sigf(iz + hz), r = sigf(ir + hr);
    float cand = tanhfast(ih + r * hh);
    float h = z * H1F[idx] + (1.f - z) * cand;
    H1F[idx] = h;
    H1B[idx] = f2bf(h);
  }
}

// logits = sigmoid(h1 @ wout + bout): 128 blocks x 64 threads, one row each.
__global__ void out_k(const float* __restrict__ h1, const float* __restrict__ wout,
                      const float* __restrict__ bout, float* __restrict__ out) {
  int row = blockIdx.x;
  int lane = threadIdx.x;
  float s = 0.f;
  for (int i = lane; i < UU; i += 64) s += h1[(size_t)row * UU + i] * wout[i];
#pragma unroll
  for (int off = 32; off > 0; off >>= 1) s += __shfl_down(s, off);
  if (lane == 0) out[row] = 1.f / (1.f + __expf(-(s + bout[0])));
}

extern "C" void kernel_launch(void* const* d_in, const int* in_sizes, int n_in,
                              void* d_out, int out_size, void* d_ws, size_t ws_size,
                              hipStream_t stream) {
  const int*   tokens = (const int*)  d_in[0];
  const float* emb    = (const float*)d_in[1];
  const float* k0     = (const float*)d_in[2];
  const float* r0     = (const float*)d_in[3];
  const float* b0     = (const float*)d_in[4];
  const float* k1     = (const float*)d_in[5];
  const float* r1     = (const float*)d_in[6];
  const float* b1     = (const float*)d_in[7];
  const float* wout   = (const float*)d_in[8];
  const float* bout   = (const float*)d_in[9];
  float* out = (float*)d_out;

  char* ws = (char*)d_ws;
  unsigned short* W0K = (unsigned short*)(ws + 0);          //  1.5 MB
  unsigned short* W0R = (unsigned short*)(ws + 1572864);    // 25.2 MB
  unsigned short* W1K = (unsigned short*)(ws + 26738688);   // 25.2 MB
  unsigned short* W1R = (unsigned short*)(ws + 51904512);   // 25.2 MB
  unsigned short* X   = (unsigned short*)(ws + 77070336);   //  2.6 MB
  float* H0F          = (float*)(ws + 79691776);            //  1 MB fp32 state
  float* H1F          = (float*)(ws + 80740352);            //  1 MB
  unsigned short* H0B = (unsigned short*)(ws + 81788928);   //  0.5 MB bf16 state
  unsigned short* H1B = (unsigned short*)(ws + 82313216);   //  0.5 MB
  float* G0           = (float*)(ws + 82837504);            //  7 MB (7 planes)
  float* G1I          = (float*)(ws + 90177536);            //  6 MB (6 planes)
  float* G1R          = (float*)(ws + 96468992);            //  6 MB (6 planes)
  // total ws use: 102,760,448 bytes

  // zero h state (H0F, H1F, H0B, H1B are contiguous): 3 MiB
  hipMemsetAsync(ws + 79691776, 0, 3145728, stream);

  // weight conversion to tiled bf16
  convert_w<<<384,  256, 0, stream>>>(k0, W0K, 100,  2);   // KC=4 (K padded to 128)
  convert_w<<<6144, 256, 0, stream>>>(r0, W0R, 2048, 6);   // KC=64
  convert_w<<<6144, 256, 0, stream>>>(k1, W1K, 2048, 6);
  convert_w<<<6144, 256, 0, stream>>>(r1, W1R, 2048, 6);

  // embedding gather (time-major, padded)
  embed_k<<<5120, 256, 0, stream>>>(tokens, emb, X);

  // 81 pipelined step dispatches: d computes h0(d) and h1(d-1) concurrently
  for (int d = 0; d <= TT; ++d) {
    step_gemms<<<768, 512, 0, stream>>>(d, X, W0K, W0R, W1K, W1R, H0B, H1B,
                                        G0, G1I, G1R);
    gates_k<<<1024, 256, 0, stream>>>(d, G0, G1I, G1R, b0, b1,
                                      H0F, H0B, H1F, H1B);
  }

  out_k<<<128, 64, 0, stream>>>(H1F, wout, bout, out);
}

// Round 5
// 3086.396 us; speedup vs baseline: 2.7484x; 1.0139x over previous
//
#include <hip/hip_runtime.h>
#include <cstdint>
#include <cstddef>

#define BB 128    // batch
#define TT 80     // seq
#define EE 100    // emb dim
#define EP 128    // padded emb dim
#define UU 2048   // units
#define G3 6144   // 3*UU
#define PLANE (BB * UU)   // 262144 elements, one gate pre-activation plane

typedef __bf16 bf16x8 __attribute__((ext_vector_type(8)));
typedef float f32x4 __attribute__((ext_vector_type(4)));

static __device__ __forceinline__ unsigned short f2bf(float x) {
  union { float f; unsigned int u; } a; a.f = x;
  unsigned int r = a.u + 0x7fffu + ((a.u >> 16) & 1u);  // RNE
  return (unsigned short)(r >> 16);
}

static __device__ __forceinline__ float sigf(float x) {
  return 1.f / (1.f + __expf(-x));
}
static __device__ __forceinline__ float tanhfast(float x) {
  return 1.f - 2.f / (__expf(2.f * x) + 1.f);
}

// Convert fp32 weight (ksrc x 6144, row-major) -> bf16 MFMA-tiled layout.
// dst element ((ct*KC + c)*64 + kb*16 + nl)*8 + j  holds  src[k=c*32+kb*8+j][col=ct*16+nl]
__global__ void convert_w(const float* __restrict__ src, unsigned short* __restrict__ dst,
                          int ksrc, int kc_shift) {
  int tid = blockIdx.x * 256 + threadIdx.x;
  int nl = tid & 15;
  int kb = (tid >> 4) & 3;
  int kc_mask = (1 << kc_shift) - 1;
  int c  = (tid >> 6) & kc_mask;
  int ct = tid >> (6 + kc_shift);
  int col = ct * 16 + nl;
  int kbase = c * 32 + kb * 8;
  union { unsigned short u[8]; int4 v; } o;
#pragma unroll
  for (int j = 0; j < 8; ++j) {
    int k = kbase + j;
    float v = (k < ksrc) ? src[(size_t)k * G3 + col] : 0.f;
    o.u[j] = f2bf(v);
  }
  *reinterpret_cast<int4*>(dst + (size_t)tid * 8) = o.v;
}

// X[t][b][e] = bf16(emb[tokens[b][t]][e]), e padded to 128 with zeros.
__global__ void embed_k(const int* __restrict__ tokens, const float* __restrict__ emb,
                        unsigned short* __restrict__ X) {
  int idx = blockIdx.x * 256 + threadIdx.x;
  int e = idx & (EP - 1);
  int b = (idx >> 7) & (BB - 1);
  int t = idx >> 14;
  float v = 0.f;
  if (e < EE) {
    int tok = tokens[b * TT + t];
    v = emb[(size_t)tok * EE + e];
  }
  X[idx] = f2bf(v);
}

// Store one f32x4 acc plane into G[m][unit]: C/D layout col=lane&15, row=kq*4+reg.
static __device__ __forceinline__ void store_plane(
    float* __restrict__ G, const f32x4& a, int tu, int wave, int lane) {
  int col = tu * 16 + (lane & 15);
  int kq = lane >> 4;
#pragma unroll
  for (int r = 0; r < 4; ++r) {
    int m = wave * 16 + kq * 4 + r;
    G[(size_t)m * UU + col] = a[r];
  }
}

// Pipelined step dispatch d (0..80): 768 blocks x 512 threads, 3 blocks/CU.
// block = grp*128 + tu;  grp = g*2 + khalf;  g: 0=L0, 1=L1-input, 2=L1-recurrent.
// Weight tile (16 cols x 1024 K x 3 gates = 96 KB) staged through VGPRs via
// regular dwordx4 loads (deep vmem queue, unlike the shallow global_load_lds
// DMA path), then ds_write_b128 into double-buffered LDS; each weight byte is
// fetched once per block; all 8 waves consume B-fragments from LDS.
__global__ __launch_bounds__(512, 6) void step_gemms(
    int d,
    const unsigned short* __restrict__ X,
    const unsigned short* __restrict__ W0K, const unsigned short* __restrict__ W0R,
    const unsigned short* __restrict__ W1K, const unsigned short* __restrict__ W1R,
    const unsigned short* __restrict__ H0B, const unsigned short* __restrict__ H1B,
    float* __restrict__ G0, float* __restrict__ G1I, float* __restrict__ G1R) {
  int grp = blockIdx.x >> 7;
  int tu = blockIdx.x & 127;
  int g = grp >> 1;
  int kh = grp & 1;
  int lane = threadIdx.x & 63;
  int wave = threadIdx.x >> 6;
  int nl = lane & 15;
  int kq = lane >> 4;
  int mrow = wave * 16 + nl;

  __shared__ unsigned short sbuf[2][24 * 512];   // 2 x 24 KB weight chunks

  const unsigned short* A;
  const unsigned short* W;
  if (g == 0)      { if (d >= TT) return; A = H0B; W = W0R; }
  else if (g == 1) { if (d <  1)  return; A = H0B; W = W1K; }
  else             { if (d <  1)  return; A = H1B; W = W1R; }

  f32x4 acc[3]  = {{0,0,0,0},{0,0,0,0},{0,0,0,0}};
  f32x4 acci[3] = {{0,0,0,0},{0,0,0,0},{0,0,0,0}};

  // role0 khalf0: tiny input projection (K=128 padded), direct loads (L2-hot)
  if (g == 0 && kh == 0) {
    const unsigned short* xp = X + (size_t)d * BB * EP + (size_t)mrow * EP + kq * 8;
    const unsigned short* wp = W0K + (size_t)tu * 4 * 512 + (size_t)lane * 8;
#pragma unroll
    for (int c = 0; c < 4; ++c) {
      bf16x8 a = *reinterpret_cast<const bf16x8*>(xp + c * 32);
#pragma unroll
      for (int gg = 0; gg < 3; ++gg) {
        bf16x8 b = *reinterpret_cast<const bf16x8*>(wp + (size_t)gg * (128 * 4 * 512) + (size_t)c * 512);
        acci[gg] = __builtin_amdgcn_mfma_f32_16x16x32_bf16(a, b, acci[gg], 0, 0, 0);
      }
    }
  }

  const int c0 = kh * 32;                      // this block's K-chunk base
  const unsigned short* ap = A + (size_t)mrow * UU + kq * 8;
  const unsigned short* wlane = W + (size_t)tu * 64 * 512 + (size_t)lane * 8;
  const size_t GS = (size_t)128 * 64 * 512;    // gate stride in tiled layout

  // prologue: load chunk 0 rows into regs, write to buf0
  int4 r0, r1, r2;
  {
    const unsigned short* src = wlane + (size_t)(c0 + wave) * 512;
    r0 = *reinterpret_cast<const int4*>(src);
    r1 = *reinterpret_cast<const int4*>(src + GS);
    r2 = *reinterpret_cast<const int4*>(src + 2 * GS);
    *reinterpret_cast<int4*>(&sbuf[0][(wave * 3 + 0) * 512 + lane * 8]) = r0;
    *reinterpret_cast<int4*>(&sbuf[0][(wave * 3 + 1) * 512 + lane * 8]) = r1;
    *reinterpret_cast<int4*>(&sbuf[0][(wave * 3 + 2) * 512 + lane * 8]) = r2;
  }
  __syncthreads();

  for (int it = 0; it < 4; ++it) {
    // issue next chunk's global loads early (deep vmem queue hides latency)
    if (it < 3) {
      const unsigned short* src = wlane + (size_t)(c0 + (it + 1) * 8 + wave) * 512;
      r0 = *reinterpret_cast<const int4*>(src);
      r1 = *reinterpret_cast<const int4*>(src + GS);
      r2 = *reinterpret_cast<const int4*>(src + 2 * GS);
    }
    // compute current chunk from LDS
#pragma unroll
    for (int h = 0; h < 2; ++h) {
      bf16x8 a[4];
#pragma unroll
      for (int j = 0; j < 4; ++j)
        a[j] = *reinterpret_cast<const bf16x8*>(ap + (size_t)(c0 + it * 8 + h * 4 + j) * 32);
#pragma unroll
      for (int j = 0; j < 4; ++j) {
#pragma unroll
        for (int gg = 0; gg < 3; ++gg) {
          bf16x8 b = *reinterpret_cast<const bf16x8*>(
              &sbuf[it & 1][((h * 4 + j) * 3 + gg) * 512 + lane * 8]);
          acc[gg] = __builtin_amdgcn_mfma_f32_16x16x32_bf16(a[j], b, acc[gg], 0, 0, 0);
        }
      }
    }
    // stash next chunk into the other LDS buffer
    if (it < 3) {
      int nb = (it + 1) & 1;
      *reinterpret_cast<int4*>(&sbuf[nb][(wave * 3 + 0) * 512 + lane * 8]) = r0;
      *reinterpret_cast<int4*>(&sbuf[nb][(wave * 3 + 1) * 512 + lane * 8]) = r1;
      *reinterpret_cast<int4*>(&sbuf[nb][(wave * 3 + 2) * 512 + lane * 8]) = r2;
    }
    __syncthreads();
  }

  // epilogue: write gate pre-activation planes
  if (g == 0) {
    if (kh == 0) {
      store_plane(G0 + 0 * PLANE, acci[0] + acc[0], tu, wave, lane);  // z partial a (+input)
      store_plane(G0 + 1 * PLANE, acci[1] + acc[1], tu, wave, lane);  // r partial a (+input)
      store_plane(G0 + 2 * PLANE, acci[2], tu, wave, lane);           // ih (full)
      store_plane(G0 + 3 * PLANE, acc[2], tu, wave, lane);            // hh partial a
    } else {
      store_plane(G0 + 4 * PLANE, acc[0], tu, wave, lane);            // z partial b
      store_plane(G0 + 5 * PLANE, acc[1], tu, wave, lane);            // r partial b
      store_plane(G0 + 6 * PLANE, acc[2], tu, wave, lane);            // hh partial b
    }
  } else if (g == 1) {
    store_plane(G1I + (kh * 3 + 0) * PLANE, acc[0], tu, wave, lane);
    store_plane(G1I + (kh * 3 + 1) * PLANE, acc[1], tu, wave, lane);
    store_plane(G1I + (kh * 3 + 2) * PLANE, acc[2], tu, wave, lane);
  } else {
    store_plane(G1R + (kh * 3 + 0) * PLANE, acc[0], tu, wave, lane);
    store_plane(G1R + (kh * 3 + 1) * PLANE, acc[1], tu, wave, lane);
    store_plane(G1R + (kh * 3 + 2) * PLANE, acc[2], tu, wave, lane);
  }
}

// Gate math + state update for dispatch d: h0(d) [d<80] and h1(d-1) [d>=1].
__global__ __launch_bounds__(256) void gates_k(
    int d,
    const float* __restrict__ G0, const float* __restrict__ G1I, const float* __restrict__ G1R,
    const float* __restrict__ b0, const float* __restrict__ b1,
    float* __restrict__ H0F, unsigned short* __restrict__ H0B,
    float* __restrict__ H1F, unsigned short* __restrict__ H1B) {
  int idx = blockIdx.x * 256 + threadIdx.x;   // (m, u) flattened, m*2048+u
  int u = idx & (UU - 1);
  if (d < TT) {
    float zs = G0[idx] + G0[4 * PLANE + idx]             + b0[u]        + b0[G3 + u];
    float rs = G0[PLANE + idx] + G0[5 * PLANE + idx]     + b0[UU + u]   + b0[G3 + UU + u];
    float ih = G0[2 * PLANE + idx]                       + b0[2 * UU + u];
    float hh = G0[3 * PLANE + idx] + G0[6 * PLANE + idx] + b0[G3 + 2 * UU + u];
    float z = sigf(zs), r = sigf(rs);
    float cand = tanhfast(ih + r * hh);
    float h = z * H0F[idx] + (1.f - z) * cand;
    H0F[idx] = h;
    H0B[idx] = f2bf(h);
  }
  if (d >= 1) {
    float iz = G1I[idx] + G1I[3 * PLANE + idx]             + b1[u];
    float ir = G1I[PLANE + idx] + G1I[4 * PLANE + idx]     + b1[UU + u];
    float ih = G1I[2 * PLANE + idx] + G1I[5 * PLANE + idx] + b1[2 * UU + u];
    float hz = G1R[idx] + G1R[3 * PLANE + idx]             + b1[G3 + u];
    float hr = G1R[PLANE + idx] + G1R[4 * PLANE + idx]     + b1[G3 + UU + u];
    float hh = G1R[2 * PLANE + idx] + G1R[5 * PLANE + idx] + b1[G3 + 2 * UU + u];
    float z = sigf(iz + hz), r = sigf(ir + hr);
    float cand = tanhfast(ih + r * hh);
    float h = z * H1F[idx] + (1.f - z) * cand;
    H1F[idx] = h;
    H1B[idx] = f2bf(h);
  }
}

// logits = sigmoid(h1 @ wout + bout): 128 blocks x 64 threads, one row each.
__global__ void out_k(const float* __restrict__ h1, const float* __restrict__ wout,
                      const float* __restrict__ bout, float* __restrict__ out) {
  int row = blockIdx.x;
  int lane = threadIdx.x;
  float s = 0.f;
  for (int i = lane; i < UU; i += 64) s += h1[(size_t)row * UU + i] * wout[i];
#pragma unroll
  for (int off = 32; off > 0; off >>= 1) s += __shfl_down(s, off);
  if (lane == 0) out[row] = 1.f / (1.f + __expf(-(s + bout[0])));
}

extern "C" void kernel_launch(void* const* d_in, const int* in_sizes, int n_in,
                              void* d_out, int out_size, void* d_ws, size_t ws_size,
                              hipStream_t stream) {
  const int*   tokens = (const int*)  d_in[0];
  const float* emb    = (const float*)d_in[1];
  const float* k0     = (const float*)d_in[2];
  const float* r0     = (const float*)d_in[3];
  const float* b0     = (const float*)d_in[4];
  const float* k1     = (const float*)d_in[5];
  const float* r1     = (const float*)d_in[6];
  const float* b1     = (const float*)d_in[7];
  const float* wout   = (const float*)d_in[8];
  const float* bout   = (const float*)d_in[9];
  float* out = (float*)d_out;

  char* ws = (char*)d_ws;
  unsigned short* W0K = (unsigned short*)(ws + 0);          //  1.5 MB
  unsigned short* W0R = (unsigned short*)(ws + 1572864);    // 25.2 MB
  unsigned short* W1K = (unsigned short*)(ws + 26738688);   // 25.2 MB
  unsigned short* W1R = (unsigned short*)(ws + 51904512);   // 25.2 MB
  unsigned short* X   = (unsigned short*)(ws + 77070336);   //  2.6 MB
  float* H0F          = (float*)(ws + 79691776);            //  1 MB fp32 state
  float* H1F          = (float*)(ws + 80740352);            //  1 MB
  unsigned short* H0B = (unsigned short*)(ws + 81788928);   //  0.5 MB bf16 state
  unsigned short* H1B = (unsigned short*)(ws + 82313216);   //  0.5 MB
  float* G0           = (float*)(ws + 82837504);            //  7 MB (7 planes)
  float* G1I          = (float*)(ws + 90177536);            //  6 MB (6 planes)
  float* G1R          = (float*)(ws + 96468992);            //  6 MB (6 planes)
  // total ws use: 102,760,448 bytes

  // zero h state (H0F, H1F, H0B, H1B are contiguous): 3 MiB
  hipMemsetAsync(ws + 79691776, 0, 3145728, stream);

  // weight conversion to tiled bf16
  convert_w<<<384,  256, 0, stream>>>(k0, W0K, 100,  2);   // KC=4 (K padded to 128)
  convert_w<<<6144, 256, 0, stream>>>(r0, W0R, 2048, 6);   // KC=64
  convert_w<<<6144, 256, 0, stream>>>(k1, W1K, 2048, 6);
  convert_w<<<6144, 256, 0, stream>>>(r1, W1R, 2048, 6);

  // embedding gather (time-major, padded)
  embed_k<<<5120, 256, 0, stream>>>(tokens, emb, X);

  // 81 pipelined step dispatches: d computes h0(d) and h1(d-1) concurrently
  for (int d = 0; d <= TT; ++d) {
    step_gemms<<<768, 512, 0, stream>>>(d, X, W0K, W0R, W1K, W1R, H0B, H1B,
                                        G0, G1I, G1R);
    gates_k<<<1024, 256, 0, stream>>>(d, G0, G1I, G1R, b0, b1,
                                      H0F, H0B, H1F, H1B);
  }

  out_k<<<128, 64, 0, stream>>>(H1F, wout, bout, out);
}